// Round 1
// 171.387 us; speedup vs baseline: 1.2117x; 1.2117x over previous
//
#include <hip/hip_runtime.h>

typedef _Float16 f16;
typedef _Float16 f16x8 __attribute__((ext_vector_type(8)));
typedef float f32x4 __attribute__((ext_vector_type(4)));

#define NN 8192
#define GG 128
#define NSPLIT 8

typedef __attribute__((address_space(3))) unsigned as3u;
typedef const __attribute__((address_space(1))) unsigned as1u;

__device__ __forceinline__ void gload16(const f16* g, f16* l) {
  __builtin_amdgcn_global_load_lds((as1u*)g, (as3u*)l, 16, 0, 0);
}

#define SBAR() asm volatile("s_barrier" ::: "memory")
#define WAITV(N) asm volatile("s_waitcnt vmcnt(" #N ")" ::: "memory")
#define WAITL0() asm volatile("s_waitcnt lgkmcnt(0)" ::: "memory")

__device__ __forceinline__ f16x8 ldcvt8(const float* p) {
  f32x4 a = *(const f32x4*)p;
  f32x4 b = *(const f32x4*)(p + 4);
  f16x8 r;
  r[0] = (f16)a[0]; r[1] = (f16)a[1]; r[2] = (f16)a[2]; r[3] = (f16)a[3];
  r[4] = (f16)b[0]; r[5] = (f16)b[1]; r[6] = (f16)b[2]; r[7] = (f16)b[3];
  return r;
}

// ---------------- wz[k] = W_k @ z0 for k=0..3 (proven rounds 6-13) ----------------
__global__ __launch_bounds__(512, 2) void k_wz(const float* __restrict__ wt,
                                               const float* __restrict__ x,
                                               f16* __restrict__ wz) {
  const int tid = (int)threadIdx.x;
  const int w = tid >> 6, l = tid & 63, lo = l & 15, hi = l >> 4;
  const int rg = w >> 1, cg = w & 1;
  const int ktap = (int)blockIdx.y;
  const int n0 = (int)blockIdx.x * 32;
  const int rowA = rg * 32;
  const float* wA0 = wt + (size_t)(rowA + lo) * 512 + (size_t)ktap * 128 + 8 * hi;
  const float* wA1 = wA0 + (size_t)16 * 512;
  const float* xB = x + (size_t)(n0 + 16 * cg + lo) * GG + 8 * hi;
  f32x4 acc[2] = {};
#pragma unroll
  for (int s = 0; s < 4; ++s) {
    f16x8 a0 = ldcvt8(wA0 + s * 32);
    f16x8 a1 = ldcvt8(wA1 + s * 32);
    f16x8 b = ldcvt8(xB + s * 32);
    acc[0] = __builtin_amdgcn_mfma_f32_16x16x32_f16(a0, b, acc[0], 0, 0, 0);
    acc[1] = __builtin_amdgcn_mfma_f32_16x16x32_f16(a1, b, acc[1], 0, 0, 0);
  }
  f16* out = wz + (size_t)ktap * (GG * NN);
#pragma unroll
  for (int fm = 0; fm < 2; ++fm)
#pragma unroll
    for (int rr = 0; rr < 4; ++rr) {
      int row = rowA + 16 * fm + 4 * hi + rr;
      out[(size_t)row * NN + n0 + 16 * cg + lo] = (f16)acc[fm][rr];
    }
}

// ---------------- fused tap1: stream S fp32 -> cvt f16 -> {LDS B (swz), Sbt} + MFMA ----
// Block (nb, ks): panel = S[ks*1024 .. +1024)[nb*128 .. +128).  Per 64-k pair:
//  8x f32x4 NT reads (dist-2, reg dbuf) -> 4x f16x8 transpose -> ds_write (XOR-swz
//  u^=(u>>6)&7) into LDS B + plain-layout global store into Sbt panel for taps 2/3.
//  A (=wz3) staged by gload16 (dist-1, LDS dbuf).  Static vmcnt counts: per iter
//  issue = 8 reads + 4 gloads + 4 stores; both steady waits land at vmcnt(20).
__global__ __launch_bounds__(256, 2) void k_tap1F(const f16* __restrict__ A,
                                                  const float* __restrict__ S,
                                                  f16* __restrict__ Sbt,
                                                  f16* __restrict__ Part) {
  __shared__ __align__(16) f16 sm[2 * 16384];  // 2 bufs x (A 16KB + B 16KB)

  const int tid = (int)threadIdx.x;
  const int w = tid >> 6, l = tid & 63, lo = l & 15, hi = l >> 4;
  const int wm = w >> 1, wn = w & 1;
  const int kg = tid >> 5, cg = tid & 31, ch = kg >> 2, khi = kg & 3;
  const int nb = (int)blockIdx.x, ks = (int)blockIdx.y;
  const int n0 = nb * 128;
  const int k0 = ks * 1024;

  const int r1 = tid >> 2, q = tid & 3;
  const f16* aS1 = A + (size_t)r1 * NN + k0 + 8 * (q ^ (r1 & 3));
  const f16* aS2 = A + (size_t)(64 + r1) * NN + k0 + 8 * (q ^ (r1 & 3));
  const float* Sb = S + (size_t)(k0 + 8 * kg) * NN + n0 + 4 * cg;
  f16* panel = Sbt + (size_t)(ks * 64 + nb) * (32 * 4096);

  f32x4 rgA[8], rgB[8];
  f32x4 acc[4][4] = {};

#define ISSUE_R(T, RG)                                                          \
  do {                                                                          \
    const float* s_ = Sb + (size_t)(64 * (T)) * NN;                             \
    _Pragma("unroll") for (int j_ = 0; j_ < 8; ++j_)                            \
        RG[j_] = __builtin_nontemporal_load((const f32x4*)(s_ + (size_t)j_ * NN)); \
  } while (0)

#define ISSUE_G(T)                                                              \
  do {                                                                          \
    f16* bA_ = sm + ((T)&1) * 16384;                                            \
    gload16(aS1 + 64 * (T), bA_ + tid * 8);                                     \
    gload16(aS2 + 64 * (T), bA_ + 2048 + tid * 8);                              \
    gload16(aS1 + 64 * (T) + 32, bA_ + 4096 + tid * 8);                         \
    gload16(aS2 + 64 * (T) + 32, bA_ + 4096 + 2048 + tid * 8);                  \
  } while (0)

#define CVT_W(T, RG)                                                            \
  do {                                                                          \
    f16* bB_ = sm + ((T)&1) * 16384 + 8192 + ch * 4096;                         \
    f16* g_ = panel + (size_t)(2 * (T) + ch) * 4096;                            \
    _Pragma("unroll") for (int i_ = 0; i_ < 4; ++i_) {                          \
      f16x8 h_;                                                                 \
      _Pragma("unroll") for (int j_ = 0; j_ < 8; ++j_) h_[j_] = (f16)RG[j_][i_]; \
      const int c_ = 4 * cg + i_;                                               \
      const int u_ = ((c_ >> 4) << 6) + (khi << 4) + (c_ & 15);                 \
      *(f16x8*)(bB_ + (size_t)(u_ ^ (cg >> 2)) * 8) = h_;                       \
      *(f16x8*)(g_ + (size_t)u_ * 8) = h_;                                      \
    }                                                                           \
  } while (0)

  auto compute2 = [&](int par) {  // one 64-k pair = 2 chunks x 16 MFMA
    const f16* base = sm + par * 16384;
#pragma unroll
    for (int cc = 0; cc < 2; ++cc) {
      const f16* Ab = base + cc * 4096;
      const f16* Bb = base + 8192 + cc * 4096;
      f16x8 af[4], bf[4];
#pragma unroll
      for (int fm = 0; fm < 4; ++fm) {
        const int row = 64 * wm + 16 * fm + lo;
        af[fm] = *(const f16x8*)(Ab + row * 32 + 8 * (hi ^ (row & 3)));
      }
#pragma unroll
      for (int fn = 0; fn < 4; ++fn) {
        const int uu = ((wn * 4 + fn) << 6) + (hi << 4) + lo;
        bf[fn] = *(const f16x8*)(Bb + (size_t)(uu ^ (wn * 4 + fn)) * 8);
      }
      WAITL0();
      __builtin_amdgcn_sched_barrier(0);
      __builtin_amdgcn_s_setprio(1);
#pragma unroll
      for (int fm = 0; fm < 4; ++fm)
#pragma unroll
        for (int fn = 0; fn < 4; ++fn)
          acc[fm][fn] = __builtin_amdgcn_mfma_f32_16x16x32_f16(af[fm], bf[fn], acc[fm][fn], 0, 0, 0);
      __builtin_amdgcn_s_setprio(0);
    }
  };

  // prologue: R(p0) R(p1) G(p0); wait R(p0) [after: 8+4=12]; cvt p0
  ISSUE_R(0, rgA);
  ISSUE_R(1, rgB);
  ISSUE_G(0);
  __builtin_amdgcn_sched_barrier(0);
  WAITV(12);
  __builtin_amdgcn_sched_barrier(0);
  CVT_W(0, rgA);
  __builtin_amdgcn_sched_barrier(0);

  for (int tt = 0; tt < 7; ++tt) {
    const int t0 = 2 * tt;
    // even body t=t0: compute pair t0 (buf0)
    ISSUE_R(t0 + 2, rgA);
    ISSUE_G(t0 + 1);
    __builtin_amdgcn_sched_barrier(0);
    WAITV(20);  // R8(p t0+1) done: after it G4+S4+R8+G4 = 20
    __builtin_amdgcn_sched_barrier(0);
    CVT_W(t0 + 1, rgB);
    __builtin_amdgcn_sched_barrier(0);
    WAITV(20);  // G4(p t0) done: after it S4+R8+G4+S4 = 20
    WAITL0();
    SBAR();
    compute2(0);
    SBAR();
    // odd body t=t0+1: compute pair t0+1 (buf1)
    ISSUE_R(t0 + 3, rgB);
    ISSUE_G(t0 + 2);
    __builtin_amdgcn_sched_barrier(0);
    WAITV(20);
    __builtin_amdgcn_sched_barrier(0);
    CVT_W(t0 + 2, rgA);
    __builtin_amdgcn_sched_barrier(0);
    WAITV(20);
    WAITL0();
    SBAR();
    compute2(1);
    SBAR();
  }
  // peeled t=14: entering outstanding = R8(p15) G4(p14) S4(p14)
  ISSUE_G(15);
  __builtin_amdgcn_sched_barrier(0);
  WAITV(12);  // R8(p15) done: after it 4+4+4
  __builtin_amdgcn_sched_barrier(0);
  CVT_W(15, rgB);
  __builtin_amdgcn_sched_barrier(0);
  WAITV(12);  // G4(p14) done: after it S4(p14)+G4(p15)+S4(p15)
  WAITL0();
  SBAR();
  compute2(0);  // pair 14
  SBAR();
  // t=15
  WAITV(4);  // G4(p15) done: after it S4(p15)
  __builtin_amdgcn_sched_barrier(0);
  SBAR();
  compute2(1);  // pair 15

#undef ISSUE_R
#undef ISSUE_G
#undef CVT_W

  f16* P = Part + (size_t)blockIdx.y * (GG * NN);
#pragma unroll
  for (int fm = 0; fm < 4; ++fm)
#pragma unroll
    for (int fn = 0; fn < 4; ++fn) {
      const int n = n0 + 64 * wn + 16 * fn + lo;
#pragma unroll
      for (int rr = 0; rr < 4; ++rr) {
        const int g = 64 * wm + 16 * fm + 4 * hi + rr;
        P[(size_t)g * NN + n] = (f16)acc[fm][fn][rr];
      }
    }
}

// ---------------- taps 2/3: proven k_tapF, NSPLIT=8 (32 steps, contiguous panels) ----
__global__ __launch_bounds__(256, 3) void k_tapF(const f16* __restrict__ A,
                                                 const f16* __restrict__ Bt,
                                                 f16* __restrict__ Part) {
  __shared__ __align__(16) f16 sm[3 * 8192];  // 3 x (A 8KB + B 8KB)

  const int tid = (int)threadIdx.x;
  const int w = tid >> 6, l = tid & 63, lo = l & 15, hi = l >> 4;
  const int wm = w >> 1, wn = w & 1;
  const int n0 = (int)blockIdx.x * 128;
  const int k0 = (int)blockIdx.y * 1024;  // NSPLIT=8 -> K=1024, 32 steps

  const int r1 = tid >> 2, r2 = 64 + (tid >> 2), q = tid & 3;
  const f16* aS1 = A + (size_t)r1 * NN + k0 + 8 * (q ^ (r1 & 3));
  const f16* aS2 = A + (size_t)r2 * NN + k0 + 8 * (q ^ (r2 & 3));
  const f16* bBlk = Bt + (size_t)((int)blockIdx.y * 64 + (int)blockIdx.x) * (32 * 4096);

#pragma unroll
  for (int p = 0; p < 2; ++p) {
    f16* buf = sm + p * 8192;
    gload16(aS1 + p * 32, buf + tid * 8);
    gload16(aS2 + p * 32, buf + 2048 + tid * 8);
    gload16(bBlk + p * 4096 + tid * 8, buf + 4096 + tid * 8);
    gload16(bBlk + p * 4096 + 2048 + tid * 8, buf + 6144 + tid * 8);
  }

  f32x4 acc[4][4] = {};

  auto compute = [&](int cur) {
    const f16* Ab = sm + cur * 8192;
    const f16* Bb = Ab + 4096;
    f16x8 af[4], bf[4];
#pragma unroll
    for (int fm = 0; fm < 4; ++fm) {
      const int row = 64 * wm + 16 * fm + lo;
      af[fm] = *(const f16x8*)(Ab + row * 32 + 8 * (hi ^ (row & 3)));
    }
#pragma unroll
    for (int fn = 0; fn < 4; ++fn)
      bf[fn] = *(const f16x8*)(Bb + (wn * 4 + fn) * 512 + hi * 128 + lo * 8);
    WAITL0();
    __builtin_amdgcn_sched_barrier(0);
    __builtin_amdgcn_s_setprio(1);
#pragma unroll
    for (int fm = 0; fm < 4; ++fm)
#pragma unroll
      for (int fn = 0; fn < 4; ++fn)
        acc[fm][fn] = __builtin_amdgcn_mfma_f32_16x16x32_f16(af[fm], bf[fn], acc[fm][fn], 0, 0, 0);
    __builtin_amdgcn_s_setprio(0);
  };

  int cur = 0, nb = 2;
  for (int t = 0; t < 30; ++t) {
    f16* buf = sm + nb * 8192;
    const int ko = (t + 2) * 32;
    gload16(aS1 + ko, buf + tid * 8);
    gload16(aS2 + ko, buf + 2048 + tid * 8);
    gload16(bBlk + (size_t)(t + 2) * 4096 + tid * 8, buf + 4096 + tid * 8);
    gload16(bBlk + (size_t)(t + 2) * 4096 + 2048 + tid * 8, buf + 6144 + tid * 8);
    __builtin_amdgcn_sched_barrier(0);
    WAITV(8);
    SBAR();
    compute(cur);
    SBAR();
    cur = (cur == 2) ? 0 : cur + 1;
    nb = (nb == 2) ? 0 : nb + 1;
  }
  WAITV(4);
  SBAR();
  compute(cur);
  SBAR();
  cur = (cur == 2) ? 0 : cur + 1;
  WAITV(0);
  SBAR();
  compute(cur);

  f16* P = Part + (size_t)blockIdx.y * (GG * NN);
#pragma unroll
  for (int fm = 0; fm < 4; ++fm)
#pragma unroll
    for (int fn = 0; fn < 4; ++fn) {
      const int n = n0 + 64 * wn + 16 * fn + lo;
#pragma unroll
      for (int rr = 0; rr < 4; ++rr) {
        const int g = 64 * wm + 16 * fm + 4 * hi + rr;
        P[(size_t)g * NN + n] = (f16)acc[fm][fn][rr];
      }
    }
}

// ---------------- combine: vectorized 16-B loads, 8 elems/thread ----------------
template <int FINAL>
__global__ void k_combine(const f16* __restrict__ Part, const f16* __restrict__ wz,
                          const float* __restrict__ bias, f16* __restrict__ tn,
                          float* __restrict__ y) {
  const int idx = (int)blockIdx.x * 512 + (int)threadIdx.x;  // 8 elems each
  const size_t off = (size_t)idx * 8;
  f16x8 wv = *(const f16x8*)(wz + off);
  float s[8];
#pragma unroll
  for (int j = 0; j < 8; ++j) s[j] = (float)wv[j];
#pragma unroll
  for (int sp = 0; sp < NSPLIT; ++sp) {
    f16x8 p = __builtin_nontemporal_load((const f16x8*)(Part + (size_t)sp * (GG * NN) + off));
#pragma unroll
    for (int j = 0; j < 8; ++j) s[j] += (float)p[j];
  }
  if (FINAL) {
    const float b = bias[(int)(off >> 13)];
    f32x4 o0, o1;
#pragma unroll
    for (int j = 0; j < 4; ++j) { o0[j] = s[j] + b; o1[j] = s[4 + j] + b; }
    *(f32x4*)(y + off) = o0;
    *(f32x4*)(y + off + 4) = o1;
  } else {
    f16x8 o;
#pragma unroll
    for (int j = 0; j < 8; ++j) o[j] = (f16)s[j];
    *(f16x8*)(tn + off) = o;
  }
}

extern "C" void kernel_launch(void* const* d_in, const int* in_sizes, int n_in, void* d_out,
                              int out_size, void* d_ws, size_t ws_size, hipStream_t stream) {
  const float* x = (const float*)d_in[0];   // [8192][128]
  const float* S = (const float*)d_in[1];   // [8192][8192] fp32
  const float* wt = (const float*)d_in[2];  // [128][1][4][128]
  const float* bs = (const float*)d_in[3];  // [128]
  float* y = (float*)d_out;                 // [128][8192] fp32
  char* ws = (char*)d_ws;

  const size_t offSbt = 0;                               // Sbt tiled f16: 134.2 MB
  const size_t offWz = offSbt + (size_t)NN * NN * 2;     // wz[4][128][8192] f16: 8 MB
  const size_t offTa = offWz + (size_t)4 * GG * NN * 2;  // t buf A: 2 MB
  const size_t offTb = offTa + (size_t)GG * NN * 2;      // t buf B: 2 MB
  const size_t offP = offTb + (size_t)GG * NN * 2;       // Part f16 [8][128][8192]: 16.8 MB
  const size_t need = offP + (size_t)NSPLIT * GG * NN * 2;
  if (ws_size < need) return;

  f16* Sbt = (f16*)(ws + offSbt);
  f16* wz = (f16*)(ws + offWz);
  f16* ta = (f16*)(ws + offTa);
  f16* tb = (f16*)(ws + offTb);
  f16* Part = (f16*)(ws + offP);

  // wz first (tap1 consumes wz3), then fused stream+tap1, then Horner chain.
  k_wz<<<dim3(256, 4), 512, 0, stream>>>(wt, x, wz);
  k_tap1F<<<dim3(64, NSPLIT), 256, 0, stream>>>(wz + (size_t)3 * GG * NN, S, Sbt, Part);
  k_combine<0><<<dim3(256), 512, 0, stream>>>(Part, wz + (size_t)2 * GG * NN, nullptr, ta, nullptr);
  k_tapF<<<dim3(64, NSPLIT), 256, 0, stream>>>(ta, Sbt, Part);
  k_combine<0><<<dim3(256), 512, 0, stream>>>(Part, wz + (size_t)1 * GG * NN, nullptr, tb, nullptr);
  k_tapF<<<dim3(64, NSPLIT), 256, 0, stream>>>(tb, Sbt, Part);
  k_combine<1><<<dim3(256), 512, 0, stream>>>(Part, wz, bs, nullptr, y);
}

// Round 2
// 171.188 us; speedup vs baseline: 1.2131x; 1.0012x over previous
//
#include <hip/hip_runtime.h>

typedef _Float16 f16;
typedef _Float16 f16x8 __attribute__((ext_vector_type(8)));
typedef float f32x4 __attribute__((ext_vector_type(4)));

#define NN 8192
#define GG 128
#define NSPLIT 8

typedef __attribute__((address_space(3))) unsigned as3u;
typedef const __attribute__((address_space(1))) unsigned as1u;

__device__ __forceinline__ void gload16(const f16* g, f16* l) {
  __builtin_amdgcn_global_load_lds((as1u*)g, (as3u*)l, 16, 0, 0);
}

#define SBAR() asm volatile("s_barrier" ::: "memory")
#define WAITV(N) asm volatile("s_waitcnt vmcnt(" #N ")" ::: "memory")
#define WAITL0() asm volatile("s_waitcnt lgkmcnt(0)" ::: "memory")

__device__ __forceinline__ f16x8 ldcvt8(const float* p) {
  f32x4 a = *(const f32x4*)p;
  f32x4 b = *(const f32x4*)(p + 4);
  f16x8 r;
  r[0] = (f16)a[0]; r[1] = (f16)a[1]; r[2] = (f16)a[2]; r[3] = (f16)a[3];
  r[4] = (f16)b[0]; r[5] = (f16)b[1]; r[6] = (f16)b[2]; r[7] = (f16)b[3];
  return r;
}

// ---------------- wz[k] = W_k @ z0 for k=0..3 (proven rounds 6-13) ----------------
__global__ __launch_bounds__(512, 2) void k_wz(const float* __restrict__ wt,
                                               const float* __restrict__ x,
                                               f16* __restrict__ wz) {
  const int tid = (int)threadIdx.x;
  const int w = tid >> 6, l = tid & 63, lo = l & 15, hi = l >> 4;
  const int rg = w >> 1, cg = w & 1;
  const int ktap = (int)blockIdx.y;
  const int n0 = (int)blockIdx.x * 32;
  const int rowA = rg * 32;
  const float* wA0 = wt + (size_t)(rowA + lo) * 512 + (size_t)ktap * 128 + 8 * hi;
  const float* wA1 = wA0 + (size_t)16 * 512;
  const float* xB = x + (size_t)(n0 + 16 * cg + lo) * GG + 8 * hi;
  f32x4 acc[2] = {};
#pragma unroll
  for (int s = 0; s < 4; ++s) {
    f16x8 a0 = ldcvt8(wA0 + s * 32);
    f16x8 a1 = ldcvt8(wA1 + s * 32);
    f16x8 b = ldcvt8(xB + s * 32);
    acc[0] = __builtin_amdgcn_mfma_f32_16x16x32_f16(a0, b, acc[0], 0, 0, 0);
    acc[1] = __builtin_amdgcn_mfma_f32_16x16x32_f16(a1, b, acc[1], 0, 0, 0);
  }
  f16* out = wz + (size_t)ktap * (GG * NN);
#pragma unroll
  for (int fm = 0; fm < 2; ++fm)
#pragma unroll
    for (int rr = 0; rr < 4; ++rr) {
      int row = rowA + 16 * fm + 4 * hi + rr;
      out[(size_t)row * NN + n0 + 16 * cg + lo] = (f16)acc[fm][rr];
    }
}

// ---------------- fused tap1: stream S fp32 -> cvt f16 -> {LDS B (swz), Sbt} + MFMA ----
// (unchanged from round 1 -- schedule proven; reg-dbuf distance-2 on S covers
//  ~2 pair-times of HBM latency, A gloads ~1 pair ahead.)
__global__ __launch_bounds__(256, 2) void k_tap1F(const f16* __restrict__ A,
                                                  const float* __restrict__ S,
                                                  f16* __restrict__ Sbt,
                                                  f16* __restrict__ Part) {
  __shared__ __align__(16) f16 sm[2 * 16384];  // 2 bufs x (A 16KB + B 16KB)

  const int tid = (int)threadIdx.x;
  const int w = tid >> 6, l = tid & 63, lo = l & 15, hi = l >> 4;
  const int wm = w >> 1, wn = w & 1;
  const int kg = tid >> 5, cg = tid & 31, ch = kg >> 2, khi = kg & 3;
  const int nb = (int)blockIdx.x, ks = (int)blockIdx.y;
  const int n0 = nb * 128;
  const int k0 = ks * 1024;

  const int r1 = tid >> 2, q = tid & 3;
  const f16* aS1 = A + (size_t)r1 * NN + k0 + 8 * (q ^ (r1 & 3));
  const f16* aS2 = A + (size_t)(64 + r1) * NN + k0 + 8 * (q ^ (r1 & 3));
  const float* Sb = S + (size_t)(k0 + 8 * kg) * NN + n0 + 4 * cg;
  f16* panel = Sbt + (size_t)(ks * 64 + nb) * (32 * 4096);

  f32x4 rgA[8], rgB[8];
  f32x4 acc[4][4] = {};

#define ISSUE_R(T, RG)                                                          \
  do {                                                                          \
    const float* s_ = Sb + (size_t)(64 * (T)) * NN;                             \
    _Pragma("unroll") for (int j_ = 0; j_ < 8; ++j_)                            \
        RG[j_] = __builtin_nontemporal_load((const f32x4*)(s_ + (size_t)j_ * NN)); \
  } while (0)

#define ISSUE_G(T)                                                              \
  do {                                                                          \
    f16* bA_ = sm + ((T)&1) * 16384;                                            \
    gload16(aS1 + 64 * (T), bA_ + tid * 8);                                     \
    gload16(aS2 + 64 * (T), bA_ + 2048 + tid * 8);                              \
    gload16(aS1 + 64 * (T) + 32, bA_ + 4096 + tid * 8);                         \
    gload16(aS2 + 64 * (T) + 32, bA_ + 4096 + 2048 + tid * 8);                  \
  } while (0)

#define CVT_W(T, RG)                                                            \
  do {                                                                          \
    f16* bB_ = sm + ((T)&1) * 16384 + 8192 + ch * 4096;                         \
    f16* g_ = panel + (size_t)(2 * (T) + ch) * 4096;                            \
    _Pragma("unroll") for (int i_ = 0; i_ < 4; ++i_) {                          \
      f16x8 h_;                                                                 \
      _Pragma("unroll") for (int j_ = 0; j_ < 8; ++j_) h_[j_] = (f16)RG[j_][i_]; \
      const int c_ = 4 * cg + i_;                                               \
      const int u_ = ((c_ >> 4) << 6) + (khi << 4) + (c_ & 15);                 \
      *(f16x8*)(bB_ + (size_t)(u_ ^ (cg >> 2)) * 8) = h_;                       \
      *(f16x8*)(g_ + (size_t)u_ * 8) = h_;                                      \
    }                                                                           \
  } while (0)

  auto compute2 = [&](int par) {  // one 64-k pair = 2 chunks x 16 MFMA
    const f16* base = sm + par * 16384;
#pragma unroll
    for (int cc = 0; cc < 2; ++cc) {
      const f16* Ab = base + cc * 4096;
      const f16* Bb = base + 8192 + cc * 4096;
      f16x8 af[4], bf[4];
#pragma unroll
      for (int fm = 0; fm < 4; ++fm) {
        const int row = 64 * wm + 16 * fm + lo;
        af[fm] = *(const f16x8*)(Ab + row * 32 + 8 * (hi ^ (row & 3)));
      }
#pragma unroll
      for (int fn = 0; fn < 4; ++fn) {
        const int uu = ((wn * 4 + fn) << 6) + (hi << 4) + lo;
        bf[fn] = *(const f16x8*)(Bb + (size_t)(uu ^ (wn * 4 + fn)) * 8);
      }
      WAITL0();
      __builtin_amdgcn_sched_barrier(0);
      __builtin_amdgcn_s_setprio(1);
#pragma unroll
      for (int fm = 0; fm < 4; ++fm)
#pragma unroll
        for (int fn = 0; fn < 4; ++fn)
          acc[fm][fn] = __builtin_amdgcn_mfma_f32_16x16x32_f16(af[fm], bf[fn], acc[fm][fn], 0, 0, 0);
      __builtin_amdgcn_s_setprio(0);
    }
  };

  // prologue: R(p0) R(p1) G(p0); wait R(p0) [after: 8+4=12]; cvt p0
  ISSUE_R(0, rgA);
  ISSUE_R(1, rgB);
  ISSUE_G(0);
  __builtin_amdgcn_sched_barrier(0);
  WAITV(12);
  __builtin_amdgcn_sched_barrier(0);
  CVT_W(0, rgA);
  __builtin_amdgcn_sched_barrier(0);

  for (int tt = 0; tt < 7; ++tt) {
    const int t0 = 2 * tt;
    // even body t=t0: compute pair t0 (buf0)
    ISSUE_R(t0 + 2, rgA);
    ISSUE_G(t0 + 1);
    __builtin_amdgcn_sched_barrier(0);
    WAITV(20);  // R8(p t0+1) done: after it G4+S4+R8+G4 = 20
    __builtin_amdgcn_sched_barrier(0);
    CVT_W(t0 + 1, rgB);
    __builtin_amdgcn_sched_barrier(0);
    WAITV(20);  // G4(p t0) done: after it S4+R8+G4+S4 = 20
    WAITL0();
    SBAR();
    compute2(0);
    SBAR();
    // odd body t=t0+1: compute pair t0+1 (buf1)
    ISSUE_R(t0 + 3, rgB);
    ISSUE_G(t0 + 2);
    __builtin_amdgcn_sched_barrier(0);
    WAITV(20);
    __builtin_amdgcn_sched_barrier(0);
    CVT_W(t0 + 2, rgA);
    __builtin_amdgcn_sched_barrier(0);
    WAITV(20);
    WAITL0();
    SBAR();
    compute2(1);
    SBAR();
  }
  // peeled t=14: entering outstanding = R8(p15) G4(p14) S4(p14)
  ISSUE_G(15);
  __builtin_amdgcn_sched_barrier(0);
  WAITV(12);  // R8(p15) done: after it 4+4+4
  __builtin_amdgcn_sched_barrier(0);
  CVT_W(15, rgB);
  __builtin_amdgcn_sched_barrier(0);
  WAITV(12);  // G4(p14) done: after it S4(p14)+G4(p15)+S4(p15)
  WAITL0();
  SBAR();
  compute2(0);  // pair 14
  SBAR();
  // t=15
  WAITV(4);  // G4(p15) done: after it S4(p15)
  __builtin_amdgcn_sched_barrier(0);
  SBAR();
  compute2(1);  // pair 15

#undef ISSUE_R
#undef ISSUE_G
#undef CVT_W

  f16* P = Part + (size_t)blockIdx.y * (GG * NN);
#pragma unroll
  for (int fm = 0; fm < 4; ++fm)
#pragma unroll
    for (int fn = 0; fn < 4; ++fn) {
      const int n = n0 + 64 * wn + 16 * fn + lo;
#pragma unroll
      for (int rr = 0; rr < 4; ++rr) {
        const int g = 64 * wm + 16 * fm + 4 * hi + rr;
        P[(size_t)g * NN + n] = (f16)acc[fm][fn][rr];
      }
    }
}

// ---------------- taps 2/3: depth-3 prefetch (4 bufs, 64 KB LDS) ----------------
// grid is 512 blocks on 256 CUs -> effective occupancy was already 2 blocks/CU,
// so growing LDS 48->64 KB costs nothing; prefetch depth 2->3 steps covers the
// ~600-900 cy global_load_lds latency (per-step compute is only ~300-400 cy).
__global__ __launch_bounds__(256, 2) void k_tapF(const f16* __restrict__ A,
                                                 const f16* __restrict__ Bt,
                                                 f16* __restrict__ Part) {
  __shared__ __align__(16) f16 sm[4 * 8192];  // 4 x (A 8KB + B 8KB)

  const int tid = (int)threadIdx.x;
  const int w = tid >> 6, l = tid & 63, lo = l & 15, hi = l >> 4;
  const int wm = w >> 1, wn = w & 1;
  const int n0 = (int)blockIdx.x * 128;
  const int k0 = (int)blockIdx.y * 1024;  // NSPLIT=8 -> K=1024, 32 steps

  const int r1 = tid >> 2, r2 = 64 + (tid >> 2), q = tid & 3;
  const f16* aS1 = A + (size_t)r1 * NN + k0 + 8 * (q ^ (r1 & 3));
  const f16* aS2 = A + (size_t)r2 * NN + k0 + 8 * (q ^ (r2 & 3));
  const f16* bBlk = Bt + (size_t)((int)blockIdx.y * 64 + (int)blockIdx.x) * (32 * 4096);

#pragma unroll
  for (int p = 0; p < 3; ++p) {
    f16* buf = sm + p * 8192;
    gload16(aS1 + p * 32, buf + tid * 8);
    gload16(aS2 + p * 32, buf + 2048 + tid * 8);
    gload16(bBlk + p * 4096 + tid * 8, buf + 4096 + tid * 8);
    gload16(bBlk + p * 4096 + 2048 + tid * 8, buf + 6144 + tid * 8);
  }

  f32x4 acc[4][4] = {};

  auto compute = [&](int cur) {
    const f16* Ab = sm + cur * 8192;
    const f16* Bb = Ab + 4096;
    f16x8 af[4], bf[4];
#pragma unroll
    for (int fm = 0; fm < 4; ++fm) {
      const int row = 64 * wm + 16 * fm + lo;
      af[fm] = *(const f16x8*)(Ab + row * 32 + 8 * (hi ^ (row & 3)));
    }
#pragma unroll
    for (int fn = 0; fn < 4; ++fn)
      bf[fn] = *(const f16x8*)(Bb + (wn * 4 + fn) * 512 + hi * 128 + lo * 8);
    WAITL0();
    __builtin_amdgcn_sched_barrier(0);
    __builtin_amdgcn_s_setprio(1);
#pragma unroll
    for (int fm = 0; fm < 4; ++fm)
#pragma unroll
      for (int fn = 0; fn < 4; ++fn)
        acc[fm][fn] = __builtin_amdgcn_mfma_f32_16x16x32_f16(af[fm], bf[fn], acc[fm][fn], 0, 0, 0);
    __builtin_amdgcn_s_setprio(0);
  };

  // steady state: issue step t+3, wait step t (16 outstanding -> 12), compute t
  for (int t = 0; t < 29; ++t) {
    f16* buf = sm + ((t + 3) & 3) * 8192;
    const int ko = (t + 3) * 32;
    gload16(aS1 + ko, buf + tid * 8);
    gload16(aS2 + ko, buf + 2048 + tid * 8);
    gload16(bBlk + (size_t)(t + 3) * 4096 + tid * 8, buf + 4096 + tid * 8);
    gload16(bBlk + (size_t)(t + 3) * 4096 + 2048 + tid * 8, buf + 6144 + tid * 8);
    __builtin_amdgcn_sched_barrier(0);
    WAITV(12);
    SBAR();
    compute(t & 3);
    SBAR();
  }
  // tail: outstanding = steps 29,30,31 (12 loads)
  WAITV(8);
  SBAR();
  compute(29 & 3);
  SBAR();
  WAITV(4);
  SBAR();
  compute(30 & 3);
  SBAR();
  WAITV(0);
  SBAR();
  compute(31 & 3);

  f16* P = Part + (size_t)blockIdx.y * (GG * NN);
#pragma unroll
  for (int fm = 0; fm < 4; ++fm)
#pragma unroll
    for (int fn = 0; fn < 4; ++fn) {
      const int n = n0 + 64 * wn + 16 * fn + lo;
#pragma unroll
      for (int rr = 0; rr < 4; ++rr) {
        const int g = 64 * wm + 16 * fm + 4 * hi + rr;
        P[(size_t)g * NN + n] = (f16)acc[fm][fn][rr];
      }
    }
}

// ---------------- combine: vectorized 16-B loads, 8 elems/thread ----------------
template <int FINAL>
__global__ void k_combine(const f16* __restrict__ Part, const f16* __restrict__ wz,
                          const float* __restrict__ bias, f16* __restrict__ tn,
                          float* __restrict__ y) {
  const int idx = (int)blockIdx.x * 512 + (int)threadIdx.x;  // 8 elems each
  const size_t off = (size_t)idx * 8;
  f16x8 wv = *(const f16x8*)(wz + off);
  float s[8];
#pragma unroll
  for (int j = 0; j < 8; ++j) s[j] = (float)wv[j];
#pragma unroll
  for (int sp = 0; sp < NSPLIT; ++sp) {
    f16x8 p = __builtin_nontemporal_load((const f16x8*)(Part + (size_t)sp * (GG * NN) + off));
#pragma unroll
    for (int j = 0; j < 8; ++j) s[j] += (float)p[j];
  }
  if (FINAL) {
    const float b = bias[(int)(off >> 13)];
    f32x4 o0, o1;
#pragma unroll
    for (int j = 0; j < 4; ++j) { o0[j] = s[j] + b; o1[j] = s[4 + j] + b; }
    __builtin_nontemporal_store(o0, (f32x4*)(y + off));
    __builtin_nontemporal_store(o1, (f32x4*)(y + off + 4));
  } else {
    f16x8 o;
#pragma unroll
    for (int j = 0; j < 8; ++j) o[j] = (f16)s[j];
    *(f16x8*)(tn + off) = o;
  }
}

extern "C" void kernel_launch(void* const* d_in, const int* in_sizes, int n_in, void* d_out,
                              int out_size, void* d_ws, size_t ws_size, hipStream_t stream) {
  const float* x = (const float*)d_in[0];   // [8192][128]
  const float* S = (const float*)d_in[1];   // [8192][8192] fp32
  const float* wt = (const float*)d_in[2];  // [128][1][4][128]
  const float* bs = (const float*)d_in[3];  // [128]
  float* y = (float*)d_out;                 // [128][8192] fp32
  char* ws = (char*)d_ws;

  const size_t offSbt = 0;                               // Sbt tiled f16: 134.2 MB
  const size_t offWz = offSbt + (size_t)NN * NN * 2;     // wz[4][128][8192] f16: 8 MB
  const size_t offTa = offWz + (size_t)4 * GG * NN * 2;  // t buf A: 2 MB
  const size_t offTb = offTa + (size_t)GG * NN * 2;      // t buf B: 2 MB
  const size_t offP = offTb + (size_t)GG * NN * 2;       // Part f16 [8][128][8192]: 16.8 MB
  const size_t need = offP + (size_t)NSPLIT * GG * NN * 2;
  if (ws_size < need) return;

  f16* Sbt = (f16*)(ws + offSbt);
  f16* wz = (f16*)(ws + offWz);
  f16* ta = (f16*)(ws + offTa);
  f16* tb = (f16*)(ws + offTb);
  f16* Part = (f16*)(ws + offP);

  // wz first (tap1 consumes wz3), then fused stream+tap1, then Horner chain.
  k_wz<<<dim3(256, 4), 512, 0, stream>>>(wt, x, wz);
  k_tap1F<<<dim3(64, NSPLIT), 256, 0, stream>>>(wz + (size_t)3 * GG * NN, S, Sbt, Part);
  k_combine<0><<<dim3(256), 512, 0, stream>>>(Part, wz + (size_t)2 * GG * NN, nullptr, ta, nullptr);
  k_tapF<<<dim3(64, NSPLIT), 256, 0, stream>>>(ta, Sbt, Part);
  k_combine<0><<<dim3(256), 512, 0, stream>>>(Part, wz + (size_t)1 * GG * NN, nullptr, tb, nullptr);
  k_tapF<<<dim3(64, NSPLIT), 256, 0, stream>>>(tb, Sbt, Part);
  k_combine<1><<<dim3(256), 512, 0, stream>>>(Part, wz, bs, nullptr, y);
}